// Round 1
// baseline (765.585 us; speedup 1.0000x reference)
//
#include <hip/hip_runtime.h>
#include <hip/hip_bf16.h>

// Problem constants (from reference setup_inputs)
#define N0 200000
#define N1 50000
#define N2 10000
#define E1 800000
#define E2 160000
// IN_F=128, HID=128, RANK=64, OUT_C=64

// ---------------------------------------------------------------------------
// zero int array
__global__ void zero_ints(int* __restrict__ a, int n) {
    int i = blockIdx.x * blockDim.x + threadIdx.x;
    if (i < n) a[i] = 0;
}

// histogram of dst indices
__global__ void hist_kernel(const int* __restrict__ dst, int* __restrict__ cnt, int E) {
    int i = blockIdx.x * blockDim.x + threadIdx.x;
    if (i < E) atomicAdd(&cnt[dst[i]], 1);
}

// single-block exclusive scan: offs[i] = prefix, cursor[i] = prefix, offs[n] = E
// cnt and cursor may alias (each thread reads own slot before writing own slot).
__global__ __launch_bounds__(1024) void scan_kernel(const int* __restrict__ cnt,
                                                    int* __restrict__ offs,
                                                    int* __restrict__ cursor,
                                                    int n, int E) {
    __shared__ int wsum[16];
    __shared__ int carry_s;
    int tid = threadIdx.x;
    int lane = tid & 63;
    int wid = tid >> 6;
    if (tid == 0) carry_s = 0;
    __syncthreads();
    for (int base = 0; base < n; base += 1024) {
        int i = base + tid;
        int v = (i < n) ? cnt[i] : 0;
        // inclusive scan within wave
        int s = v;
        #pragma unroll
        for (int off = 1; off < 64; off <<= 1) {
            int t = __shfl_up(s, off, 64);
            if (lane >= off) s += t;
        }
        if (lane == 63) wsum[wid] = s;
        __syncthreads();
        if (wid == 0) {
            int ws = (lane < 16) ? wsum[lane] : 0;
            #pragma unroll
            for (int off = 1; off < 16; off <<= 1) {
                int t = __shfl_up(ws, off, 64);
                if (lane >= off) ws += t;
            }
            if (lane < 16) wsum[lane] = ws;  // inclusive scan of wave sums
        }
        __syncthreads();
        int wexcl = (wid == 0) ? 0 : wsum[wid - 1];
        int carry = carry_s;
        int excl = carry + wexcl + (s - v);
        if (i < n) {
            offs[i] = excl;
            cursor[i] = excl;
        }
        __syncthreads();
        if (tid == 1023) carry_s = carry + wsum[15];
        __syncthreads();
    }
    if (tid == 0) offs[n] = E;
}

// scatter edges into CSR order: sorted[pos] = src[e]
__global__ void scatter_kernel(const int* __restrict__ dst, const int* __restrict__ src,
                               int* __restrict__ cursor, int* __restrict__ sorted, int E) {
    int i = blockIdx.x * blockDim.x + threadIdx.x;
    if (i < E) {
        int p = atomicAdd(&cursor[dst[i]], 1);
        sorted[p] = src[i];
    }
}

// ---------------------------------------------------------------------------
// Thread-per-row GEMM: out[M x N] = A[M x K] @ W[K x N] (+bias) (+relu)
// W/bias accesses are wave-uniform -> scalar loads; acc[N] lives in VGPRs.
template <int K, int N, bool RELU, bool BIAS>
__global__ __launch_bounds__(256) void rowmm(const float* __restrict__ A,
                                             const float* __restrict__ W,
                                             const float* __restrict__ bias,
                                             float* __restrict__ out, int M) {
    int row = blockIdx.x * blockDim.x + threadIdx.x;
    if (row >= M) return;
    const float* Ar = A + (size_t)row * K;
    float acc[N];
    #pragma unroll
    for (int c = 0; c < N; ++c) acc[c] = BIAS ? bias[c] : 0.0f;
    for (int k = 0; k < K; k += 4) {
        float4 a = *reinterpret_cast<const float4*>(Ar + k);
        float av[4] = {a.x, a.y, a.z, a.w};
        #pragma unroll
        for (int j = 0; j < 4; ++j) {
            const float* Wr = W + (size_t)(k + j) * N;
            #pragma unroll
            for (int c = 0; c < N; ++c) acc[c] = fmaf(av[j], Wr[c], acc[c]);
        }
    }
    float* o = out + (size_t)row * N;
    #pragma unroll
    for (int c = 0; c < N; c += 4) {
        float4 v;
        v.x = acc[c + 0]; v.y = acc[c + 1]; v.z = acc[c + 2]; v.w = acc[c + 3];
        if (RELU) {
            v.x = fmaxf(v.x, 0.0f); v.y = fmaxf(v.y, 0.0f);
            v.z = fmaxf(v.z, 0.0f); v.w = fmaxf(v.w, 0.0f);
        }
        *reinterpret_cast<float4*>(o + c) = v;
    }
}

// ---------------------------------------------------------------------------
// One wave per dst node; lane = feature (RANK=64 == wavefront size).
// z[d][lane] = (mean over incoming edges of hsrc[src][lane]) * hdst_z[d][lane]
// written in-place into hdst_z.
__global__ __launch_bounds__(256) void agg_mul(const float* __restrict__ hsrc,
                                               const int* __restrict__ offs,
                                               const int* __restrict__ sorted,
                                               float* __restrict__ hdst_z, int ndst) {
    int wid = threadIdx.x >> 6;
    int lane = threadIdx.x & 63;
    int d = blockIdx.x * 4 + wid;
    if (d >= ndst) return;
    int start = offs[d];
    int end = offs[d + 1];
    float acc = 0.0f;
    for (int e = start; e < end; ++e) {
        int s = sorted[e];
        acc += hsrc[(size_t)s * 64 + lane];
    }
    int cnt = end - start;
    float inv = (cnt > 0) ? (1.0f / (float)cnt) : 0.0f;
    size_t idx = (size_t)d * 64 + lane;
    hdst_z[idx] = acc * inv * hdst_z[idx];
}

// ---------------------------------------------------------------------------
extern "C" void kernel_launch(void* const* d_in, const int* in_sizes, int n_in,
                              void* d_out, int out_size, void* d_ws, size_t ws_size,
                              hipStream_t stream) {
    const float* x     = (const float*)d_in[0];
    const float* Wsrc1 = (const float*)d_in[1];
    const float* Wdst1 = (const float*)d_in[2];
    const float* Wout1 = (const float*)d_in[3];
    const float* b1    = (const float*)d_in[4];
    const float* Wsrc2 = (const float*)d_in[5];
    const float* Wdst2 = (const float*)d_in[6];
    const float* Wout2 = (const float*)d_in[7];
    const float* b2    = (const float*)d_in[8];
    const int* src1    = (const int*)d_in[9];
    const int* dst1    = (const int*)d_in[10];
    const int* src2    = (const int*)d_in[11];
    const int* dst2    = (const int*)d_in[12];
    float* out = (float*)d_out;

    // workspace layout (all fp32 buffers fully written before read)
    float* f = (float*)d_ws;
    float* hsrc1 = f;                          // N0*64 (later reused as hsrc2: N1*64)
    float* hdst1 = hsrc1 + (size_t)N0 * 64;    // N1*64 (becomes z1 in-place)
    float* h     = hdst1 + (size_t)N1 * 64;    // N1*128
    float* hdst2 = h + (size_t)N1 * 128;       // N2*64 (becomes z2 in-place)
    int* ip = (int*)(hdst2 + (size_t)N2 * 64);
    int* offs1   = ip; ip += N1 + 1;
    int* cur1    = ip; ip += N1;
    int* sorted1 = ip; ip += E1;
    int* offs2   = ip; ip += N2 + 1;
    int* cur2    = ip; ip += N2;
    int* sorted2 = ip; ip += E2;

    // --- CSR build for both layers ---
    zero_ints<<<(N1 + 255) / 256, 256, 0, stream>>>(cur1, N1);
    zero_ints<<<(N2 + 255) / 256, 256, 0, stream>>>(cur2, N2);
    hist_kernel<<<(E1 + 255) / 256, 256, 0, stream>>>(dst1, cur1, E1);
    hist_kernel<<<(E2 + 255) / 256, 256, 0, stream>>>(dst2, cur2, E2);
    scan_kernel<<<1, 1024, 0, stream>>>(cur1, offs1, cur1, N1, E1);
    scan_kernel<<<1, 1024, 0, stream>>>(cur2, offs2, cur2, N2, E2);
    scatter_kernel<<<(E1 + 255) / 256, 256, 0, stream>>>(dst1, src1, cur1, sorted1, E1);
    scatter_kernel<<<(E2 + 255) / 256, 256, 0, stream>>>(dst2, src2, cur2, sorted2, E2);

    // --- layer 1 ---
    rowmm<128, 64, false, false><<<(N0 + 255) / 256, 256, 0, stream>>>(x, Wsrc1, nullptr, hsrc1, N0);
    rowmm<128, 64, false, false><<<(N1 + 255) / 256, 256, 0, stream>>>(x, Wdst1, nullptr, hdst1, N1);
    agg_mul<<<(N1 + 3) / 4, 256, 0, stream>>>(hsrc1, offs1, sorted1, hdst1, N1);
    rowmm<64, 128, true, true><<<(N1 + 255) / 256, 256, 0, stream>>>(hdst1, Wout1, b1, h, N1);

    // --- layer 2 (hsrc1 buffer reused for hsrc2) ---
    rowmm<128, 64, false, false><<<(N1 + 255) / 256, 256, 0, stream>>>(h, Wsrc2, nullptr, hsrc1, N1);
    rowmm<128, 64, false, false><<<(N2 + 255) / 256, 256, 0, stream>>>(h, Wdst2, nullptr, hdst2, N2);
    agg_mul<<<(N2 + 3) / 4, 256, 0, stream>>>(hsrc1, offs2, sorted2, hdst2, N2);
    rowmm<64, 64, false, true><<<(N2 + 255) / 256, 256, 0, stream>>>(hdst2, Wout2, b2, out, N2);
}

// Round 2
// 579.447 us; speedup vs baseline: 1.3212x; 1.3212x over previous
//
#include <hip/hip_runtime.h>
#include <hip/hip_bf16.h>

// Problem constants (from reference setup_inputs)
#define N0 200000
#define N1 50000
#define N2 10000
#define E1C 800000
#define E2C 160000
// IN_F=128, HID=128, RANK=64, OUT_C=64

// ---------------------------------------------------------------------------
__global__ void zero_ints(int* __restrict__ a, int n) {
    int i = blockIdx.x * blockDim.x + threadIdx.x;
    if (i < n) a[i] = 0;
}

// fused histogram of both layers' dst indices
__global__ void hist_dual(const int* __restrict__ d1, int* __restrict__ c1, int e1,
                          const int* __restrict__ d2, int* __restrict__ c2, int e2) {
    int i = blockIdx.x * blockDim.x + threadIdx.x;
    if (i < e1) {
        atomicAdd(&c1[d1[i]], 1);
    } else {
        int j = i - e1;
        if (j < e2) atomicAdd(&c2[d2[j]], 1);
    }
}

// ---------------------------------------------------------------------------
// 3-phase exclusive scan (block chunk = 1024 elements, 256 threads x int4)

// phase 1: per-chunk sums for both arrays in one grid
__global__ __launch_bounds__(256) void scan_partial_dual(
    const int* __restrict__ c1, int n1, int* __restrict__ p1, int B1,
    const int* __restrict__ c2, int n2, int* __restrict__ p2) {
    const int* c; int n; int* p; int b;
    if ((int)blockIdx.x < B1) { c = c1; n = n1; p = p1; b = blockIdx.x; }
    else { c = c2; n = n2; p = p2; b = blockIdx.x - B1; }
    int base = b * 1024 + threadIdx.x * 4;
    int s = 0;
    if (base < n) {  // n % 4 == 0 for both layers -> full int4 in-bounds
        int4 v = *reinterpret_cast<const int4*>(c + base);
        s = v.x + v.y + v.z + v.w;
    }
    #pragma unroll
    for (int o = 32; o > 0; o >>= 1) s += __shfl_xor(s, o, 64);
    __shared__ int ws[4];
    if ((threadIdx.x & 63) == 0) ws[threadIdx.x >> 6] = s;
    __syncthreads();
    if (threadIdx.x == 0) p[b] = ws[0] + ws[1] + ws[2] + ws[3];
}

// phase 2: single wave scans both partial arrays (lens <= 64)
__global__ void scan_mid(int* __restrict__ p1, int n1, int* __restrict__ p2, int n2) {
    int lane = threadIdx.x;
    int v = (lane < n1) ? p1[lane] : 0;
    int s = v;
    #pragma unroll
    for (int o = 1; o < 64; o <<= 1) { int t = __shfl_up(s, o, 64); if (lane >= o) s += t; }
    if (lane < n1) p1[lane] = s - v;
    int v2 = (lane < n2) ? p2[lane] : 0;
    int s2 = v2;
    #pragma unroll
    for (int o = 1; o < 64; o <<= 1) { int t = __shfl_up(s2, o, 64); if (lane >= o) s2 += t; }
    if (lane < n2) p2[lane] = s2 - v2;
}

// phase 3: per-element exclusive scan; writes offs[] and cursor[] (cursor aliases cnt)
__global__ __launch_bounds__(256) void scan_final_dual(
    int* __restrict__ c1, int* __restrict__ offs1, int n1, int e1, const int* __restrict__ p1, int B1,
    int* __restrict__ c2, int* __restrict__ offs2, int n2, int e2, const int* __restrict__ p2) {
    int* c; int* offs; int n; int e; const int* p; int b;
    if ((int)blockIdx.x < B1) { c = c1; offs = offs1; n = n1; e = e1; p = p1; b = blockIdx.x; }
    else { c = c2; offs = offs2; n = n2; e = e2; p = p2; b = blockIdx.x - B1; }
    int tid = threadIdx.x, lane = tid & 63, wid = tid >> 6;
    int base = b * 1024 + tid * 4;
    int4 v = make_int4(0, 0, 0, 0);
    if (base < n) v = *reinterpret_cast<const int4*>(c + base);
    int s4 = v.x + v.y + v.z + v.w;
    int s = s4;
    #pragma unroll
    for (int o = 1; o < 64; o <<= 1) { int t = __shfl_up(s, o, 64); if (lane >= o) s += t; }
    __shared__ int wsum[4];
    if (lane == 63) wsum[wid] = s;
    __syncthreads();
    int wbase = 0;
    #pragma unroll
    for (int w = 0; w < 4; ++w) if (w < wid) wbase += wsum[w];
    int excl = p[b] + wbase + (s - s4);
    if (base < n) {
        int o0 = excl, o1 = o0 + v.x, o2 = o1 + v.y, o3 = o2 + v.z;
        int4 ov = make_int4(o0, o1, o2, o3);
        *reinterpret_cast<int4*>(offs + base) = ov;
        *reinterpret_cast<int4*>(c + base) = ov;  // cursor
    }
    if (b == 0 && tid == 0) offs[n] = e;
}

// fused scatter for both layers: sorted[pos] = src[e]
__global__ void scatter_dual(const int* __restrict__ d1, const int* __restrict__ s1,
                             int* __restrict__ cur1, int* __restrict__ so1, int e1,
                             const int* __restrict__ d2, const int* __restrict__ s2,
                             int* __restrict__ cur2, int* __restrict__ so2, int e2) {
    int i = blockIdx.x * blockDim.x + threadIdx.x;
    if (i < e1) {
        int p = atomicAdd(&cur1[d1[i]], 1);
        so1[p] = s1[i];
    } else {
        int j = i - e1;
        if (j < e2) {
            int p = atomicAdd(&cur2[d2[j]], 1);
            so2[p] = s2[j];
        }
    }
}

// ---------------------------------------------------------------------------
// Thread-per-row GEMM body: out[row][c0..c0+63] for each 64-col chunk of NTOT.
// W/bias accesses wave-uniform -> scalar loads; acc[64] in VGPRs.
template <int K, int NTOT, bool RELU, bool BIAS>
__device__ __forceinline__ void rowmm_body(const float* __restrict__ A,
                                           const float* __restrict__ W,
                                           const float* __restrict__ bias,
                                           float* __restrict__ out, int row, int M) {
    if (row >= M) return;
    const float* Ar = A + (size_t)row * K;
    float* Or = out + (size_t)row * NTOT;
    #pragma unroll
    for (int c0 = 0; c0 < NTOT; c0 += 64) {
        float acc[64];
        #pragma unroll
        for (int c = 0; c < 64; ++c) acc[c] = BIAS ? bias[c0 + c] : 0.0f;
        #pragma unroll 4
        for (int k = 0; k < K; k += 4) {
            float4 a = *reinterpret_cast<const float4*>(Ar + k);
            float av[4] = {a.x, a.y, a.z, a.w};
            #pragma unroll
            for (int j = 0; j < 4; ++j) {
                const float* Wr = W + (size_t)(k + j) * NTOT + c0;
                #pragma unroll
                for (int c = 0; c < 64; ++c) acc[c] = fmaf(av[j], Wr[c], acc[c]);
            }
        }
        #pragma unroll
        for (int c = 0; c < 64; c += 4) {
            float4 v;
            v.x = acc[c + 0]; v.y = acc[c + 1]; v.z = acc[c + 2]; v.w = acc[c + 3];
            if (RELU) {
                v.x = fmaxf(v.x, 0.0f); v.y = fmaxf(v.y, 0.0f);
                v.z = fmaxf(v.z, 0.0f); v.w = fmaxf(v.w, 0.0f);
            }
            *reinterpret_cast<float4*>(Or + c0 + c) = v;
        }
    }
}

template <int K, int NTOT, bool RELU, bool BIAS>
__global__ __launch_bounds__(256, 1) void rowmm(const float* __restrict__ A,
                                                const float* __restrict__ W,
                                                const float* __restrict__ bias,
                                                float* __restrict__ out, int M) {
    int row = blockIdx.x * 256 + threadIdx.x;
    rowmm_body<K, NTOT, RELU, BIAS>(A, W, bias, out, row, M);
}

// two independent skinny GEMMs sharing the same A base, split at block Ba
template <int K, int NTOT>
__global__ __launch_bounds__(256, 1) void rowmm_dual(const float* __restrict__ A,
                                                     const float* __restrict__ Wa,
                                                     float* __restrict__ outa, int Ma, int Ba,
                                                     const float* __restrict__ Wb,
                                                     float* __restrict__ outb, int Mb) {
    if ((int)blockIdx.x < Ba) {
        int row = blockIdx.x * 256 + threadIdx.x;
        rowmm_body<K, NTOT, false, false>(A, Wa, nullptr, outa, row, Ma);
    } else {
        int row = (blockIdx.x - Ba) * 256 + threadIdx.x;
        rowmm_body<K, NTOT, false, false>(A, Wb, nullptr, outb, row, Mb);
    }
}

// ---------------------------------------------------------------------------
// One wave per dst node. lane = (edge_slot = lane>>4, float4_chunk = lane&15).
// 4 edges in flight per iteration, 16B gathers; cross-lane reduce at the end.
// z (in-place) = mean(hsrc[src]) * z
__global__ __launch_bounds__(256) void agg_mul(const float* __restrict__ hsrc,
                                               const int* __restrict__ offs,
                                               const int* __restrict__ sorted,
                                               float* __restrict__ z, int ndst) {
    int wid = threadIdx.x >> 6;
    int lane = threadIdx.x & 63;
    int d = blockIdx.x * 4 + wid;
    if (d >= ndst) return;
    int start = offs[d];
    int end = offs[d + 1];
    int sub = lane >> 4;
    int fq = lane & 15;
    float4 acc = make_float4(0.f, 0.f, 0.f, 0.f);
    for (int e = start + sub; e < end; e += 4) {
        int sidx = sorted[e];
        float4 v = *reinterpret_cast<const float4*>(hsrc + (size_t)sidx * 64 + fq * 4);
        acc.x += v.x; acc.y += v.y; acc.z += v.z; acc.w += v.w;
    }
    #pragma unroll
    for (int o = 16; o <= 32; o <<= 1) {
        acc.x += __shfl_xor(acc.x, o, 64);
        acc.y += __shfl_xor(acc.y, o, 64);
        acc.z += __shfl_xor(acc.z, o, 64);
        acc.w += __shfl_xor(acc.w, o, 64);
    }
    if (sub == 0) {
        int cnt = end - start;
        float inv = (cnt > 0) ? (1.0f / (float)cnt) : 0.0f;
        size_t idx = (size_t)d * 64 + fq * 4;
        float4 hd = *reinterpret_cast<const float4*>(z + idx);
        float4 r;
        r.x = acc.x * inv * hd.x; r.y = acc.y * inv * hd.y;
        r.z = acc.z * inv * hd.z; r.w = acc.w * inv * hd.w;
        *reinterpret_cast<float4*>(z + idx) = r;
    }
}

// ---------------------------------------------------------------------------
extern "C" void kernel_launch(void* const* d_in, const int* in_sizes, int n_in,
                              void* d_out, int out_size, void* d_ws, size_t ws_size,
                              hipStream_t stream) {
    const float* x     = (const float*)d_in[0];
    const float* Wsrc1 = (const float*)d_in[1];
    const float* Wdst1 = (const float*)d_in[2];
    const float* Wout1 = (const float*)d_in[3];
    const float* b1    = (const float*)d_in[4];
    const float* Wsrc2 = (const float*)d_in[5];
    const float* Wdst2 = (const float*)d_in[6];
    const float* Wout2 = (const float*)d_in[7];
    const float* b2    = (const float*)d_in[8];
    const int* src1    = (const int*)d_in[9];
    const int* dst1    = (const int*)d_in[10];
    const int* src2    = (const int*)d_in[11];
    const int* dst2    = (const int*)d_in[12];
    float* out = (float*)d_out;

    // workspace layout
    float* f = (float*)d_ws;
    float* hsrc1 = f;                          // N0*64 (reused as hsrc2)
    float* hdst1 = hsrc1 + (size_t)N0 * 64;    // N1*64 (becomes z1 in-place)
    float* h     = hdst1 + (size_t)N1 * 64;    // N1*128
    float* hdst2 = h + (size_t)N1 * 128;       // N2*64 (becomes z2 in-place)
    int* ip = (int*)(hdst2 + (size_t)N2 * 64);
    int* cur1    = ip; ip += N1;               // cur1,cur2 contiguous for fused zero
    int* cur2    = ip; ip += N2;
    int* offs1   = ip; ip += N1 + 4;
    int* offs2   = ip; ip += N2 + 4;
    int* sorted1 = ip; ip += E1C;
    int* sorted2 = ip; ip += E2C;
    int* part1   = ip; ip += 52;
    int* part2   = ip; ip += 12;

    const int B1 = (N1 + 1023) / 1024;   // 49
    const int B2 = (N2 + 1023) / 1024;   // 10

    // --- CSR build for both layers ---
    zero_ints<<<(N1 + N2 + 255) / 256, 256, 0, stream>>>(cur1, N1 + N2);
    hist_dual<<<(E1C + E2C + 255) / 256, 256, 0, stream>>>(dst1, cur1, E1C, dst2, cur2, E2C);
    scan_partial_dual<<<B1 + B2, 256, 0, stream>>>(cur1, N1, part1, B1, cur2, N2, part2);
    scan_mid<<<1, 64, 0, stream>>>(part1, B1, part2, B2);
    scan_final_dual<<<B1 + B2, 256, 0, stream>>>(cur1, offs1, N1, E1C, part1, B1,
                                                 cur2, offs2, N2, E2C, part2);
    scatter_dual<<<(E1C + E2C + 255) / 256, 256, 0, stream>>>(dst1, src1, cur1, sorted1, E1C,
                                                              dst2, src2, cur2, sorted2, E2C);

    // --- layer 1 ---
    {
        int Ba = (N0 + 255) / 256, Bb = (N1 + 255) / 256;
        rowmm_dual<128, 64><<<Ba + Bb, 256, 0, stream>>>(x, Wsrc1, hsrc1, N0, Ba,
                                                         Wdst1, hdst1, N1);
    }
    agg_mul<<<(N1 + 3) / 4, 256, 0, stream>>>(hsrc1, offs1, sorted1, hdst1, N1);
    rowmm<64, 128, true, true><<<(N1 + 255) / 256, 256, 0, stream>>>(hdst1, Wout1, b1, h, N1);

    // --- layer 2 (hsrc1 buffer reused as hsrc2) ---
    {
        int Ba = (N1 + 255) / 256, Bb = (N2 + 255) / 256;
        rowmm_dual<128, 64><<<Ba + Bb, 256, 0, stream>>>(h, Wsrc2, hsrc1, N1, Ba,
                                                         Wdst2, hdst2, N2);
    }
    agg_mul<<<(N2 + 3) / 4, 256, 0, stream>>>(hsrc1, offs2, sorted2, hdst2, N2);
    rowmm<64, 64, false, true><<<(N2 + 255) / 256, 256, 0, stream>>>(hdst2, Wout2, b2, out, N2);
}